// Round 1
// baseline (5310.000 us; speedup 1.0000x reference)
//
#include <hip/hip_runtime.h>

#define NE 400
#define NIN 784
#define BB 512
#define TT 50

// constants, rounded from double exactly as jax traces them
constexpr float C_KE     = (float)(0.5 / 100.0);   // DT/TAU_MEM_E
constexpr float C_KI     = (float)(0.5 / 10.0);    // DT/TAU_MEM_I
constexpr float C_GSE    = 0.5f;                   // DT/TAU_SYN_E
constexpr float C_GSI    = 0.25f;                  // DT/TAU_SYN_I
constexpr float C_DECTH  = (float)(1.0 - 0.5 / 1e7);
constexpr float C_DEC1   = (float)(1.0 - 0.5 / 20.0);  // post trace 1
constexpr float C_DEC2   = (float)(1.0 - 0.5 / 40.0);  // post trace 2
constexpr float C_DECPRE = (float)(1.0 - 0.5 / 20.0);  // pre trace
constexpr float C_NUPRE  = (float)0.0001;
constexpr float C_NUPOST = 0.01f;

__global__ void k_init(float* g_ine, float* g_ei, float* g_ie, float* Iie,
                       float* mem_e, float* rc_e, float* mem_i, float* rc_i,
                       float* theta, float* tp1, float* tp2) {
    int i = blockIdx.x * blockDim.x + threadIdx.x;
    if (i < BB * NE) {
        g_ine[i] = 0.f; g_ei[i] = 0.f; g_ie[i] = 0.f; Iie[i] = 0.f;
        mem_e[i] = -65.0f; rc_e[i] = 0.f;
        mem_i[i] = -60.0f; rc_i[i] = 0.f;
        theta[i] = 20.0f; tp1[i] = 0.f; tp2[i] = 0.f;
    }
}

// W row normalization: Wn = W / (rowsum(W)/78.4)
__global__ __launch_bounds__(256) void k_rownorm(const float* __restrict__ W,
                                                 float* __restrict__ Wn) {
    int row = blockIdx.x;
    int tid = threadIdx.x;
    __shared__ float red[256];
    float s = 0.f;
    for (int i = tid; i < NIN; i += 256) s += W[row * NIN + i];
    red[tid] = s;
    __syncthreads();
    for (int off = 128; off > 0; off >>= 1) {
        if (tid < off) red[tid] += red[tid + off];
        __syncthreads();
    }
    float d = red[0] / 78.4f;
    for (int i = tid; i < NIN; i += 256) Wn[row * NIN + i] = W[row * NIN + i] / d;
}

// dg_ine[b,e] = sum_i xt[b,i] * Wn[e,i]   (NT gemm, both K-contiguous)
#define TK1 32
__global__ __launch_bounds__(256) void k_gemm1(const float* __restrict__ x,
                                               const float* __restrict__ Wn,
                                               float* __restrict__ dg) {
    __shared__ float xs[16][TK1 + 1];
    __shared__ float ws[16][TK1 + 1];
    int tx = threadIdx.x, ty = threadIdx.y;
    int e0 = blockIdx.x * 16, b0 = blockIdx.y * 16;
    int lid = ty * 16 + tx;
    float acc = 0.f;
    for (int k0 = 0; k0 < NIN; k0 += TK1) {
        int kw = NIN - k0; if (kw > TK1) kw = TK1;
        for (int l = lid; l < 16 * TK1; l += 256) {
            int r = l >> 5, c = l & 31;
            xs[r][c] = (c < kw) ? x[(b0 + r) * NIN + k0 + c] : 0.f;
            ws[r][c] = (c < kw) ? Wn[(e0 + r) * NIN + k0 + c] : 0.f;
        }
        __syncthreads();
#pragma unroll
        for (int k = 0; k < TK1; k++) acc += xs[ty][k] * ws[tx][k];
        __syncthreads();
    }
    dg[(b0 + ty) * NE + (e0 + tx)] = acc;
}

// pre-synaptic trace update
__global__ void k_trpre(const float* __restrict__ xt, float* __restrict__ tr, int t) {
    int i = blockIdx.x * blockDim.x + threadIdx.x;
    if (i < BB * NIN) {
        float xv = xt[i];
        if (t == 0) {
            tr[i] = xv;
        } else {
            float v = tr[i] * C_DECPRE;
            tr[i] = (xv > 0.9f) ? 1.0f : v;
        }
    }
}

// full elementwise phase: LIF-e, e->i (diag), LIF-i, i->e (ones-eye via row sum),
// theta homeostasis, post traces, STDP operand prep
__global__ __launch_bounds__(512) void k_ephase(const float* __restrict__ dg_ine,
                                                float* g_ine, float* g_ei, float* g_ie,
                                                float* Iie, float* mem_e, float* rc_e,
                                                float* mem_i, float* rc_i, float* theta,
                                                float* tp1, float* tp2,
                                                float* __restrict__ A1,
                                                float* __restrict__ A2,
                                                float* __restrict__ out_t) {
    int b = blockIdx.x;
    int e = threadIdx.x;
    __shared__ float red[512];
    int idx = b * NE + e;

    float spk_i = 0.f, spk_e = 0.f;
    float g1 = 0.f, me = 0.f, re = 0.f, th = 0.f, g2 = 0.f, mi = 0.f, ri = 0.f;

    if (e < NE) {
        float dg = dg_ine[idx];
        g1 = g_ine[idx]; me = mem_e[idx]; re = rc_e[idx];
        th = theta[idx];
        float Ii = Iie[idx];
        // input->e current uses OLD g_ine, OLD mem_e
        float I_in = g1 * (0.0f - me);
        g1 = g1 + (dg - g1) * C_GSE;
        // excitatory LIF
        bool act = (re <= 0.0f);
        float I = I_in + Ii;
        if (act) me = me + ((-65.0f - me) + I) * C_KE;
        re = fmaxf(re - 0.5f, 0.0f);
        float thr = -72.0f + th;
        spk_e = (act && (me > thr)) ? 1.0f : 0.0f;
        if (spk_e > 0.0f) { me = -65.0f; re = 5.0f; }
        // e->i (W_ei = 10.4*I exactly)
        float dgei = spk_e * 10.4f;
        g2 = g_ei[idx]; mi = mem_i[idx]; ri = rc_i[idx];
        float I_ei = g2 * (0.0f - mi);
        g2 = g2 + (dgei - g2) * C_GSE;
        // inhibitory LIF
        bool ai = (ri <= 0.0f);
        if (ai) mi = mi + ((-60.0f - mi) + I_ei) * C_KI;
        ri = fmaxf(ri - 0.5f, 0.0f);
        spk_i = (ai && (mi > -40.0f)) ? 1.0f : 0.0f;
        if (spk_i > 0.0f) { mi = -45.0f; ri = 2.0f; }
    }
    red[e] = spk_i;
    __syncthreads();
    for (int off = 256; off > 0; off >>= 1) {
        if (e < off) red[e] += red[e + off];
        __syncthreads();
    }
    float S = red[0];  // integer-valued: exact in any sum order
    if (e < NE) {
        // i->e (W_ie = 17*(1-I) exactly)
        float dgie = 17.0f * (S - spk_i);
        float g3 = g_ie[idx];
        float Iie_new = g3 * (-100.0f - me);  // NEW mem_e
        g3 = g3 + (dgie - g3) * C_GSI;
        // threshold homeostasis
        th = th * C_DECTH + 0.05f * spk_e;
        // post traces (return decayed, then set 1 where fired)
        float r1 = tp1[idx] * C_DEC1;
        float r2 = tp2[idx] * C_DEC2;
        bool fired = spk_e > 0.9f;
        A1[idx] = r1;
        A2[idx] = spk_e * r2;
        tp1[idx] = fired ? 1.0f : r1;
        tp2[idx] = fired ? 1.0f : r2;
        g_ine[idx] = g1; g_ei[idx] = g2; g_ie[idx] = g3; Iie[idx] = Iie_new;
        mem_e[idx] = me; rc_e[idx] = re; mem_i[idx] = mi; rc_i[idx] = ri;
        theta[idx] = th;
        out_t[idx] = spk_e;
    }
}

// W[e,i] = clip(Wn[e,i] + NU_PRE*sum_b A1[b,e]*xt[b,i] + NU_POST*sum_b A2[b,e]*tr[b,i], 0, 1)
#define TK2 32
__global__ __launch_bounds__(256) void k_gemm2(const float* __restrict__ A1,
                                               const float* __restrict__ A2,
                                               const float* __restrict__ xt,
                                               const float* __restrict__ tr,
                                               const float* __restrict__ Wn,
                                               float* __restrict__ W) {
    __shared__ float a1s[TK2][17];
    __shared__ float a2s[TK2][17];
    __shared__ float xs[TK2][17];
    __shared__ float ts[TK2][17];
    int tx = threadIdx.x, ty = threadIdx.y;
    int i0 = blockIdx.x * 16, e0 = blockIdx.y * 16;
    int lid = ty * 16 + tx;
    float s1 = 0.f, s2 = 0.f;
    for (int b0 = 0; b0 < BB; b0 += TK2) {
        for (int l = lid; l < TK2 * 16; l += 256) {
            int r = l >> 4, c = l & 15;
            a1s[r][c] = A1[(b0 + r) * NE + e0 + c];
            a2s[r][c] = A2[(b0 + r) * NE + e0 + c];
            xs[r][c]  = xt[(b0 + r) * NIN + i0 + c];
            ts[r][c]  = tr[(b0 + r) * NIN + i0 + c];
        }
        __syncthreads();
#pragma unroll
        for (int k = 0; k < TK2; k++) {
            s1 += a1s[k][ty] * xs[k][tx];
            s2 += a2s[k][ty] * ts[k][tx];
        }
        __syncthreads();
    }
    int oi = (e0 + ty) * NIN + (i0 + tx);
    float w = Wn[oi] + C_NUPRE * s1 + C_NUPOST * s2;
    W[oi] = fminf(fmaxf(w, 0.0f), 1.0f);
}

extern "C" void kernel_launch(void* const* d_in, const int* in_sizes, int n_in,
                              void* d_out, int out_size, void* d_ws, size_t ws_size,
                              hipStream_t stream) {
    const float* x     = (const float*)d_in[0];  // (50, 512, 784)
    const float* W_ine = (const float*)d_in[1];  // (400, 784)
    // d_in[2] = W_ei (10.4*I), d_in[3] = W_ie (17*(1-I)) -- structure used directly

    float* p = (float*)d_ws;
    float* W_cur = p; p += NE * NIN;       // evolving weights
    float* Wn    = p; p += NE * NIN;       // normalized weights (per step)
    float* dg    = p; p += BB * NE;        // dg_ine
    float* A1    = p; p += BB * NE;        // ret1
    float* A2    = p; p += BB * NE;        // spike_e * ret2
    float* g_ine = p; p += BB * NE;
    float* g_ei  = p; p += BB * NE;
    float* g_ie  = p; p += BB * NE;
    float* Iie   = p; p += BB * NE;
    float* mem_e = p; p += BB * NE;
    float* rc_e  = p; p += BB * NE;
    float* mem_i = p; p += BB * NE;
    float* rc_i  = p; p += BB * NE;
    float* theta = p; p += BB * NE;
    float* tp1   = p; p += BB * NE;
    float* tp2   = p; p += BB * NE;
    float* tr    = p; p += BB * NIN;       // pre trace

    hipMemcpyAsync(W_cur, W_ine, (size_t)NE * NIN * sizeof(float),
                   hipMemcpyDeviceToDevice, stream);
    k_init<<<(BB * NE + 255) / 256, 256, 0, stream>>>(g_ine, g_ei, g_ie, Iie, mem_e,
                                                      rc_e, mem_i, rc_i, theta, tp1, tp2);

    for (int t = 0; t < TT; t++) {
        const float* xt = x + (size_t)t * BB * NIN;
        float* out_t = (float*)d_out + (size_t)t * BB * NE;
        k_rownorm<<<NE, 256, 0, stream>>>(W_cur, Wn);
        k_gemm1<<<dim3(NE / 16, BB / 16), dim3(16, 16), 0, stream>>>(xt, Wn, dg);
        k_trpre<<<(BB * NIN + 255) / 256, 256, 0, stream>>>(xt, tr, t);
        k_ephase<<<BB, 512, 0, stream>>>(dg, g_ine, g_ei, g_ie, Iie, mem_e, rc_e,
                                         mem_i, rc_i, theta, tp1, tp2, A1, A2, out_t);
        k_gemm2<<<dim3(NIN / 16, NE / 16), dim3(16, 16), 0, stream>>>(A1, A2, xt, tr,
                                                                      Wn, W_cur);
    }
}

// Round 2
// 2606.527 us; speedup vs baseline: 2.0372x; 2.0372x over previous
//
#include <hip/hip_runtime.h>

#define NE 400
#define NIN 784
#define BB 512
#define TT 50

#define KC1 7          // gemm1 K-chunks (784 = 7*112)
#define KCH1 112
#define KC2 4          // gemm2 K-chunks (512 = 4*128)
#define KCH2 128

constexpr float C_KE     = (float)(0.5 / 100.0);
constexpr float C_KI     = (float)(0.5 / 10.0);
constexpr float C_GSE    = 0.5f;
constexpr float C_GSI    = 0.25f;
constexpr float C_DECTH  = (float)(1.0 - 0.5 / 1e7);
constexpr float C_DEC1   = (float)(1.0 - 0.5 / 20.0);
constexpr float C_DEC2   = (float)(1.0 - 0.5 / 40.0);
constexpr float C_DECPRE = (float)(1.0 - 0.5 / 20.0);
constexpr float C_NUPRE  = (float)0.0001;
constexpr float C_NUPOST = 0.01f;

__global__ void k_init(float* g_ine, float* g_ei, float* g_ie, float* Iie,
                       float* mem_e, float* rc_e, float* mem_i, float* rc_i,
                       float* theta, float* tp1, float* tp2) {
    int i = blockIdx.x * blockDim.x + threadIdx.x;
    if (i < BB * NE) {
        g_ine[i] = 0.f; g_ei[i] = 0.f; g_ie[i] = 0.f; Iie[i] = 0.f;
        mem_e[i] = -65.0f; rc_e[i] = 0.f;
        mem_i[i] = -60.0f; rc_i[i] = 0.f;
        theta[i] = 20.0f; tp1[i] = 0.f; tp2[i] = 0.f;
    }
}

// initial d[e] = rowsum(W)/78.4
__global__ __launch_bounds__(256) void k_rowsum0(const float* __restrict__ W,
                                                 float* __restrict__ d) {
    int e = blockIdx.x, tid = threadIdx.x;
    __shared__ float red[256];
    float s = 0.f;
    if (tid < 196) {
        float4 w = *(const float4*)&W[e * NIN + tid * 4];
        s = w.x + w.y + w.z + w.w;
    }
    red[tid] = s;
    __syncthreads();
    for (int off = 128; off > 0; off >>= 1) {
        if (tid < off) red[tid] += red[tid + off];
        __syncthreads();
    }
    if (tid == 0) d[e] = red[0] / 78.4f;
}

// gemm1 partials: dgp[kc][b][e] = sum_{k in chunk} x[b,k]*W[e,k]  (NT)
// 64x64 tile, 4x4 per thread, K-tile 16
__global__ __launch_bounds__(256) void k_gemm1(const float* __restrict__ x,
                                               const float* __restrict__ W,
                                               float* __restrict__ dgp) {
    __shared__ float xs[16][68];  // [k][b_local]
    __shared__ float ws[16][68];  // [k][e_local]
    int tx = threadIdx.x & 15, ty = threadIdx.x >> 4;
    int lid = threadIdx.x;
    int e0 = blockIdx.x * 64, b0 = blockIdx.y * 64;
    int kbase = blockIdx.z * KCH1;

    float acc[4][4];
#pragma unroll
    for (int r = 0; r < 4; r++)
#pragma unroll
        for (int c = 0; c < 4; c++) acc[r][c] = 0.f;

    for (int kt = 0; kt < KCH1; kt += 16) {
        int k0 = kbase + kt;
        // stage: 64 rows x 16 k each, transposed into [k][row]
        {
            int r = lid >> 2, cb = (lid & 3) * 4;
            float4 xv = *(const float4*)&x[(b0 + r) * NIN + k0 + cb];
            xs[cb + 0][r] = xv.x; xs[cb + 1][r] = xv.y;
            xs[cb + 2][r] = xv.z; xs[cb + 3][r] = xv.w;
            float4 wv;
            if (e0 + r < NE) wv = *(const float4*)&W[(e0 + r) * NIN + k0 + cb];
            else wv = make_float4(0.f, 0.f, 0.f, 0.f);
            ws[cb + 0][r] = wv.x; ws[cb + 1][r] = wv.y;
            ws[cb + 2][r] = wv.z; ws[cb + 3][r] = wv.w;
        }
        __syncthreads();
#pragma unroll
        for (int k = 0; k < 16; k++) {
            float4 av = *(const float4*)&xs[k][ty * 4];
            float4 bv = *(const float4*)&ws[k][tx * 4];
            float a[4] = {av.x, av.y, av.z, av.w};
            float b[4] = {bv.x, bv.y, bv.z, bv.w};
#pragma unroll
            for (int r = 0; r < 4; r++)
#pragma unroll
                for (int c = 0; c < 4; c++) acc[r][c] += a[r] * b[c];
        }
        __syncthreads();
    }
    if (e0 + tx * 4 < NE) {
        float* base = dgp + (size_t)blockIdx.z * BB * NE;
#pragma unroll
        for (int r = 0; r < 4; r++) {
            float4 v = make_float4(acc[r][0], acc[r][1], acc[r][2], acc[r][3]);
            *(float4*)&base[(b0 + ty * 4 + r) * NE + e0 + tx * 4] = v;
        }
    }
}

// fused: blocks [0,512) = per-batch LIF/elementwise phase; blocks [512,708) = pre-trace
__global__ __launch_bounds__(512) void k_mid(const float* __restrict__ dgp,
                                             const float* __restrict__ d,
                                             const float* __restrict__ xt,
                                             float* __restrict__ tr, int t,
                                             float* g_ine, float* g_ei, float* g_ie,
                                             float* Iie, float* mem_e, float* rc_e,
                                             float* mem_i, float* rc_i, float* theta,
                                             float* tp1, float* tp2,
                                             float* __restrict__ A1,
                                             float* __restrict__ A2,
                                             float* __restrict__ out_t) {
    if (blockIdx.x >= BB) {
        // pre-trace update: 2048 elements per block, float4
        int base = (blockIdx.x - BB) * 2048 + threadIdx.x * 4;
        float4 xv = *(const float4*)&xt[base];
        float4 o;
        if (t == 0) {
            o = xv;
        } else {
            float4 tv = *(const float4*)&tr[base];
            o.x = (xv.x > 0.9f) ? 1.0f : tv.x * C_DECPRE;
            o.y = (xv.y > 0.9f) ? 1.0f : tv.y * C_DECPRE;
            o.z = (xv.z > 0.9f) ? 1.0f : tv.z * C_DECPRE;
            o.w = (xv.w > 0.9f) ? 1.0f : tv.w * C_DECPRE;
        }
        *(float4*)&tr[base] = o;
        return;
    }
    int b = blockIdx.x;
    int e = threadIdx.x;
    __shared__ float red[512];
    int idx = b * NE + e;

    float spk_i = 0.f, spk_e = 0.f;
    float g1 = 0.f, me = 0.f, re = 0.f, th = 0.f, g2 = 0.f, mi = 0.f, ri = 0.f;

    if (e < NE) {
        float dg = 0.f;
#pragma unroll
        for (int c = 0; c < KC1; c++) dg += dgp[(size_t)c * BB * NE + idx];
        dg = dg / d[e];
        g1 = g_ine[idx]; me = mem_e[idx]; re = rc_e[idx];
        th = theta[idx];
        float Ii = Iie[idx];
        float I_in = g1 * (0.0f - me);
        g1 = g1 + (dg - g1) * C_GSE;
        bool act = (re <= 0.0f);
        float I = I_in + Ii;
        if (act) me = me + ((-65.0f - me) + I) * C_KE;
        re = fmaxf(re - 0.5f, 0.0f);
        float thr = -72.0f + th;
        spk_e = (act && (me > thr)) ? 1.0f : 0.0f;
        if (spk_e > 0.0f) { me = -65.0f; re = 5.0f; }
        float dgei = spk_e * 10.4f;
        g2 = g_ei[idx]; mi = mem_i[idx]; ri = rc_i[idx];
        float I_ei = g2 * (0.0f - mi);
        g2 = g2 + (dgei - g2) * C_GSE;
        bool ai = (ri <= 0.0f);
        if (ai) mi = mi + ((-60.0f - mi) + I_ei) * C_KI;
        ri = fmaxf(ri - 0.5f, 0.0f);
        spk_i = (ai && (mi > -40.0f)) ? 1.0f : 0.0f;
        if (spk_i > 0.0f) { mi = -45.0f; ri = 2.0f; }
    }
    red[e] = spk_i;
    __syncthreads();
    for (int off = 256; off > 0; off >>= 1) {
        if (e < off) red[e] += red[e + off];
        __syncthreads();
    }
    float S = red[0];  // integer-valued: exact in any order
    if (e < NE) {
        float dgie = 17.0f * (S - spk_i);
        float g3 = g_ie[idx];
        float Iie_new = g3 * (-100.0f - me);
        g3 = g3 + (dgie - g3) * C_GSI;
        th = th * C_DECTH + 0.05f * spk_e;
        float r1 = tp1[idx] * C_DEC1;
        float r2 = tp2[idx] * C_DEC2;
        bool fired = spk_e > 0.9f;
        A1[idx] = r1;
        A2[idx] = spk_e * r2;
        tp1[idx] = fired ? 1.0f : r1;
        tp2[idx] = fired ? 1.0f : r2;
        g_ine[idx] = g1; g_ei[idx] = g2; g_ie[idx] = g3; Iie[idx] = Iie_new;
        mem_e[idx] = me; rc_e[idx] = re; mem_i[idx] = mi; rc_i[idx] = ri;
        theta[idx] = th;
        out_t[idx] = spk_e;
    }
}

// gemm2 partials: part[kc][e][i] = NU_PRE*sum_b A1[b,e]*x[b,i] + NU_POST*sum_b A2[b,e]*tr[b,i]
// 64(e) x 64(i) tile, 4x4 per thread, K-tile 16 over b
__global__ __launch_bounds__(256) void k_gemm2(const float* __restrict__ A1,
                                               const float* __restrict__ A2,
                                               const float* __restrict__ xt,
                                               const float* __restrict__ tr,
                                               float* __restrict__ part) {
    __shared__ float a1s[16][68];
    __shared__ float a2s[16][68];
    __shared__ float xs[16][68];
    __shared__ float ts[16][68];
    int tx = threadIdx.x & 15, ty = threadIdx.x >> 4;
    int lid = threadIdx.x;
    int i0 = blockIdx.x * 64, e0 = blockIdx.y * 64;
    int bbase = blockIdx.z * KCH2;

    float s1[4][4], s2[4][4];
#pragma unroll
    for (int r = 0; r < 4; r++)
#pragma unroll
        for (int c = 0; c < 4; c++) { s1[r][c] = 0.f; s2[r][c] = 0.f; }

    for (int bt = 0; bt < KCH2; bt += 16) {
        int b0 = bbase + bt;
        {
            int r = lid >> 4, cb = (lid & 15) * 4;
            float4 v1, v2;
            if (e0 + cb < NE) {
                v1 = *(const float4*)&A1[(b0 + r) * NE + e0 + cb];
                v2 = *(const float4*)&A2[(b0 + r) * NE + e0 + cb];
            } else {
                v1 = make_float4(0.f, 0.f, 0.f, 0.f);
                v2 = v1;
            }
            *(float4*)&a1s[r][cb] = v1;
            *(float4*)&a2s[r][cb] = v2;
            float4 xv, tv;
            if (i0 + cb < NIN) {
                xv = *(const float4*)&xt[(b0 + r) * NIN + i0 + cb];
                tv = *(const float4*)&tr[(b0 + r) * NIN + i0 + cb];
            } else {
                xv = make_float4(0.f, 0.f, 0.f, 0.f);
                tv = xv;
            }
            *(float4*)&xs[r][cb] = xv;
            *(float4*)&ts[r][cb] = tv;
        }
        __syncthreads();
#pragma unroll
        for (int k = 0; k < 16; k++) {
            float4 a1v = *(const float4*)&a1s[k][ty * 4];
            float4 a2v = *(const float4*)&a2s[k][ty * 4];
            float4 xv = *(const float4*)&xs[k][tx * 4];
            float4 tv = *(const float4*)&ts[k][tx * 4];
            float a1[4] = {a1v.x, a1v.y, a1v.z, a1v.w};
            float a2[4] = {a2v.x, a2v.y, a2v.z, a2v.w};
            float xx[4] = {xv.x, xv.y, xv.z, xv.w};
            float tt[4] = {tv.x, tv.y, tv.z, tv.w};
#pragma unroll
            for (int r = 0; r < 4; r++)
#pragma unroll
                for (int c = 0; c < 4; c++) {
                    s1[r][c] += a1[r] * xx[c];
                    s2[r][c] += a2[r] * tt[c];
                }
        }
        __syncthreads();
    }
    if (e0 + ty * 4 < NE && i0 + tx * 4 < NIN) {
        float* base = part + (size_t)blockIdx.z * NE * NIN;
#pragma unroll
        for (int r = 0; r < 4; r++) {
            float4 v = make_float4(C_NUPRE * s1[r][0] + C_NUPOST * s2[r][0],
                                   C_NUPRE * s1[r][1] + C_NUPOST * s2[r][1],
                                   C_NUPRE * s1[r][2] + C_NUPOST * s2[r][2],
                                   C_NUPRE * s1[r][3] + C_NUPOST * s2[r][3]);
            *(float4*)&base[(e0 + ty * 4 + r) * NIN + i0 + tx * 4] = v;
        }
    }
}

// W[e,i] = clip(W[e,i]/d[e] + sum_c part[c][e,i], 0, 1); d[e] = rowsum(W_new)/78.4
__global__ __launch_bounds__(256) void k_wupdate(float* __restrict__ W,
                                                 const float* __restrict__ part,
                                                 float* __restrict__ d) {
    int e = blockIdx.x, tid = threadIdx.x;
    __shared__ float red[256];
    float dv = d[e];
    float s = 0.f;
    if (tid < 196) {
        int off = e * NIN + tid * 4;
        float4 w = *(const float4*)&W[off];
        float4 acc = make_float4(w.x / dv, w.y / dv, w.z / dv, w.w / dv);
#pragma unroll
        for (int c = 0; c < KC2; c++) {
            float4 p = *(const float4*)&part[(size_t)c * NE * NIN + off];
            acc.x += p.x; acc.y += p.y; acc.z += p.z; acc.w += p.w;
        }
        acc.x = fminf(fmaxf(acc.x, 0.f), 1.f);
        acc.y = fminf(fmaxf(acc.y, 0.f), 1.f);
        acc.z = fminf(fmaxf(acc.z, 0.f), 1.f);
        acc.w = fminf(fmaxf(acc.w, 0.f), 1.f);
        *(float4*)&W[off] = acc;
        s = acc.x + acc.y + acc.z + acc.w;
    }
    red[tid] = s;
    __syncthreads();
    for (int off = 128; off > 0; off >>= 1) {
        if (tid < off) red[tid] += red[tid + off];
        __syncthreads();
    }
    if (tid == 0) d[e] = red[0] / 78.4f;
}

extern "C" void kernel_launch(void* const* d_in, const int* in_sizes, int n_in,
                              void* d_out, int out_size, void* d_ws, size_t ws_size,
                              hipStream_t stream) {
    const float* x     = (const float*)d_in[0];  // (50, 512, 784)
    const float* W_ine = (const float*)d_in[1];  // (400, 784)

    float* p = (float*)d_ws;
    float* W_cur = p; p += NE * NIN;
    float* dbuf  = p; p += NE;                   // row divisor d[e]
    float* dgp   = p; p += (size_t)KC1 * BB * NE;   // gemm1 partials
    float* part  = p; p += (size_t)KC2 * NE * NIN;  // gemm2 partials
    float* A1    = p; p += BB * NE;
    float* A2    = p; p += BB * NE;
    float* g_ine = p; p += BB * NE;
    float* g_ei  = p; p += BB * NE;
    float* g_ie  = p; p += BB * NE;
    float* Iie   = p; p += BB * NE;
    float* mem_e = p; p += BB * NE;
    float* rc_e  = p; p += BB * NE;
    float* mem_i = p; p += BB * NE;
    float* rc_i  = p; p += BB * NE;
    float* theta = p; p += BB * NE;
    float* tp1   = p; p += BB * NE;
    float* tp2   = p; p += BB * NE;
    float* tr    = p; p += BB * NIN;

    hipMemcpyAsync(W_cur, W_ine, (size_t)NE * NIN * sizeof(float),
                   hipMemcpyDeviceToDevice, stream);
    k_init<<<(BB * NE + 255) / 256, 256, 0, stream>>>(g_ine, g_ei, g_ie, Iie, mem_e,
                                                      rc_e, mem_i, rc_i, theta, tp1, tp2);
    k_rowsum0<<<NE, 256, 0, stream>>>(W_cur, dbuf);

    for (int t = 0; t < TT; t++) {
        const float* xt = x + (size_t)t * BB * NIN;
        float* out_t = (float*)d_out + (size_t)t * BB * NE;
        k_gemm1<<<dim3(7, 8, KC1), 256, 0, stream>>>(xt, W_cur, dgp);
        k_mid<<<BB + 196, 512, 0, stream>>>(dgp, dbuf, xt, tr, t, g_ine, g_ei, g_ie,
                                            Iie, mem_e, rc_e, mem_i, rc_i, theta,
                                            tp1, tp2, A1, A2, out_t);
        k_gemm2<<<dim3(13, 7, KC2), 256, 0, stream>>>(A1, A2, xt, tr, part);
        k_wupdate<<<NE, 256, 0, stream>>>(W_cur, part, dbuf);
    }
}